// Round 10
// baseline (121.393 us; speedup 1.0000x reference)
//
#include <hip/hip_runtime.h>

// DR splitting solver. BATCH=4096, N=96 (64 x + 32 s), M=48 (16 eq + 32 ineq).
// JF and Hessian are batch-independent => prox_g1 is an affine map y = P x + Bmat p.
//   S=(I+Q)^{-1}; T=S Jx^T; K2=Jx T+diag(0,I32); R2=K2^{-1}[T^T|E];
//   P=diag(S,I)-[T;E^T]R2; Bmat=[-P[:,:64] | R2^T]
// Iterate 10x: y=Px+c; x += clamp(2y-x,l,u)-y; out=y[:64].
//
// Round-9 lesson: both kernels LDS-LATENCY-bound (R=1->R=2 on iter barely moved
// it; prep at 256 thr = 1 wave/SIMD). Round-10: prep -> 512 threads (2/SIMD,
// 2x4 GJ tiles); iter -> explicit 1-ahead x prefetch inside the dot loop.

__device__ __forceinline__ float dot4f(float4 a, float4 b) {
  return a.x*b.x + a.y*b.y + a.z*b.z + a.w*b.w;
}
__device__ __forceinline__ void ld4(const float* p, float* d) {
  float4 v = *(const float4*)p;
  d[0] = v.x; d[1] = v.y; d[2] = v.z; d[3] = v.w;
}
__device__ __forceinline__ void st4(float* p, const float* s) {
  *(float4*)p = make_float4(s[0], s[1], s[2], s[3]);
}
__device__ __forceinline__ float fastrcp(float x) {
  float r = __builtin_amdgcn_rcpf(x);
  return r * (2.0f - x * r);     // 1 Newton step: ~1e-7 rel
}
// in-place 4x4 inverse by GJ, no pivoting (SPD principal blocks)
__device__ __forceinline__ void inv4(float D[4][4]) {
  #pragma unroll
  for (int p = 0; p < 4; ++p) {
    float pi = fastrcp(D[p][p]);
    D[p][p] = pi;
    #pragma unroll
    for (int q = 0; q < 4; ++q) if (q != p) D[p][q] *= pi;
    #pragma unroll
    for (int i = 0; i < 4; ++i) if (i != p) {
      float f = D[i][p];
      #pragma unroll
      for (int q = 0; q < 4; ++q) if (q != p) D[i][q] -= f * D[p][q];
      D[i][p] = -f * pi;
    }
  }
}

// one double-buffered block-GJ step, 2 rows x 4 cols per thread.
// thread (ig2, jg4) owns rows {2ig2, 2ig2+1} x col-quad 4jg4.
__device__ __forceinline__ void gj_2x4(const float* __restrict__ src,
                                       float* __restrict__ dst,
                                       int b, int ig2, int jg4, int stride,
                                       bool act) {
  if (act) {
    float D[4][4], C[2][4], R[4][4], T2[2][4], W[2][4];
    #pragma unroll
    for (int r = 0; r < 4; ++r) {
      ld4(&src[(4*b + r)*stride + 4*b],   D[r]);
      ld4(&src[(4*b + r)*stride + 4*jg4], R[r]);
    }
    ld4(&src[(2*ig2 + 0)*stride + 4*b], C[0]);
    ld4(&src[(2*ig2 + 1)*stride + 4*b], C[1]);
    ld4(&src[(2*ig2 + 0)*stride + 4*jg4], T2[0]);
    ld4(&src[(2*ig2 + 1)*stride + 4*jg4], T2[1]);
    inv4(D);
    const int ri = (ig2 & 1) * 2;
    if ((ig2 >> 1) == b) {
      if (jg4 == b) {
        #pragma unroll
        for (int i = 0; i < 2; ++i)
          #pragma unroll
          for (int q = 0; q < 4; ++q) W[i][q] = D[ri + i][q];
      } else {
        #pragma unroll
        for (int i = 0; i < 2; ++i)
          #pragma unroll
          for (int q = 0; q < 4; ++q) {
            float s = D[ri + i][0] * R[0][q];
            #pragma unroll
            for (int k = 1; k < 4; ++k) s += D[ri + i][k] * R[k][q];
            W[i][q] = s;
          }
      }
    } else {
      float E[2][4];
      #pragma unroll
      for (int i = 0; i < 2; ++i)
        #pragma unroll
        for (int k = 0; k < 4; ++k) {
          float s = C[i][0] * D[0][k];
          #pragma unroll
          for (int m = 1; m < 4; ++m) s += C[i][m] * D[m][k];
          E[i][k] = s;
        }
      if (jg4 == b) {
        #pragma unroll
        for (int i = 0; i < 2; ++i)
          #pragma unroll
          for (int q = 0; q < 4; ++q) W[i][q] = -E[i][q];
      } else {
        #pragma unroll
        for (int i = 0; i < 2; ++i)
          #pragma unroll
          for (int q = 0; q < 4; ++q) {
            float s = T2[i][q];
            #pragma unroll
            for (int k = 0; k < 4; ++k) s -= E[i][k] * R[k][q];
            W[i][q] = s;
          }
      }
    }
    st4(&dst[(2*ig2 + 0)*stride + 4*jg4], W[0]);
    st4(&dst[(2*ig2 + 1)*stride + 4*jg4], W[1]);
  }
  __syncthreads();
}

// ---------------------------------------------------------------- kernel A
__global__ __launch_bounds__(512, 1) void prep_kernel(
    const float* __restrict__ Qg, const float* __restrict__ Ag,
    const float* __restrict__ Gg,
    float* __restrict__ Pg, float* __restrict__ Bg)
{
  // floats: 4352 + 4352 + 2496 + 4608 = 15808 = 63232 B
  __shared__ float sMa[64*68];   // M1 ping  -> S (after 16 steps)
  __shared__ float sMb[64*68];   // M1 pong  -> T (64x48, stride 48)
  __shared__ float sK [48*52];   // K2 ping  -> Ki
  __shared__ float sR2[48*96];   // Jx (s68) -> K2 pong (s52) -> R2 (s96)

#define SM_(i,j) sMa[(i)*68+(j)]
#define TT_(i,j) sMb[(i)*48+(j)]
#define SK_(i,j) sK[(i)*52+(j)]
#define JX_(a,k) sR2[(a)*68+(k)]

  const int tid = threadIdx.x;   // 0..511

  // ---- stage Jx = [A;G] (48x64, stride 68) and M1 = Q + I
  {
    const float4* A4 = (const float4*)Ag;          // 256 quads
    const float4* G4 = (const float4*)Gg;          // 512 quads
    const float4* Q4 = (const float4*)Qg;          // 1024 quads
    if (tid < 256) {
      int a = tid >> 4, kc = tid & 15;
      st4(&JX_(a, kc*4), (const float*)&A4[tid]);
    }
    {
      int a = tid >> 4, kc = tid & 15;
      st4(&JX_(16 + a, kc*4), (const float*)&G4[tid]);
    }
    #pragma unroll
    for (int t = tid; t < 1024; t += 512) {
      int i = t >> 4, kc = t & 15;
      st4(&SM_(i, kc*4), (const float*)&Q4[t]);
    }
  }
  __syncthreads();
  if (tid < 64) SM_(tid, tid) += 1.0f;
  __syncthreads();

  // ---- block-GJ 64 (dbuf, 1 barrier/step, 16 steps) -> S in sMa
  {
    const int ig2 = tid >> 4, jg4 = tid & 15;      // 32 x 16 tile grid
    #pragma unroll 1
    for (int p = 0; p < 8; ++p) {
      gj_2x4(sMa, sMb, 2*p,     ig2, jg4, 68, true);
      gj_2x4(sMb, sMa, 2*p + 1, ig2, jg4, 68, true);
    }
  }

  // ---- T = S Jx^T : 2x3 register tile/thread (32 ig x 16 jg covers 64x48)
  {
    const int i0 = 2*(tid >> 4), j0 = 3*(tid & 15);
    float acc[2][3] = {};
    #pragma unroll 4
    for (int kq = 0; kq < 16; ++kq) {
      float sv[2][4], jv[3][4];
      ld4(&SM_(i0+0, kq*4), sv[0]); ld4(&SM_(i0+1, kq*4), sv[1]);
      ld4(&JX_(j0+0, kq*4), jv[0]); ld4(&JX_(j0+1, kq*4), jv[1]);
      ld4(&JX_(j0+2, kq*4), jv[2]);
      #pragma unroll
      for (int r = 0; r < 2; ++r)
        #pragma unroll
        for (int c = 0; c < 3; ++c)
          #pragma unroll
          for (int s = 0; s < 4; ++s)
            acc[r][c] += sv[r][s] * jv[c][s];
    }
    // sMb (pong) free to write: last read of it finished at GJ64's final barrier
    #pragma unroll
    for (int r = 0; r < 2; ++r)
      #pragma unroll
      for (int c = 0; c < 3; ++c)
        TT_(i0+r, j0+c) = acc[r][c];
  }
  __syncthreads();

  // ---- K2 = Jx T + diag(0,I32)  (288 threads, 2x4 tiles)
  if (tid < 288) {
    int a0 = 2*(tid / 12), b0 = 4*(tid % 12);
    float acc[2][4] = {};
    #pragma unroll 4
    for (int k = 0; k < 64; ++k) {
      float4 tb = *(const float4*)&TT_(k, b0);
      float j0v = JX_(a0 + 0, k);
      float j1v = JX_(a0 + 1, k);
      acc[0][0] += j0v*tb.x; acc[0][1] += j0v*tb.y;
      acc[0][2] += j0v*tb.z; acc[0][3] += j0v*tb.w;
      acc[1][0] += j1v*tb.x; acc[1][1] += j1v*tb.y;
      acc[1][2] += j1v*tb.z; acc[1][3] += j1v*tb.w;
    }
    #pragma unroll
    for (int r = 0; r < 2; ++r)
      #pragma unroll
      for (int q = 0; q < 4; ++q) {
        int a = a0 + r, b = b0 + q;
        SK_(a, b) = acc[r][q] + ((a == b && a >= 16) ? 1.0f : 0.0f);
      }
  }
  __syncthreads();

  // ---- block-GJ 48 (dbuf; pong overlays dead Jx region) -> Ki in sK
  {
    float* KP = sR2;   // 48*52 = 2496 <= 4608
    const bool act = tid < 288;                    // 24 x 12 tile grid
    const int ig2 = tid / 12, jg4 = tid - (tid / 12) * 12;
    #pragma unroll 1
    for (int p = 0; p < 6; ++p) {
      gj_2x4(sK, KP, 2*p,     ig2, jg4, 52, act);
      gj_2x4(KP, sK, 2*p + 1, ig2, jg4, 52, act);
    }
  }
  // KP / JX dead; sR2 region becomes R2 (stride 96).

  // ---- R2 cols<64: R2[k][c] = sum_m Ki[k][m]*T[c][m]  (384 thr, 2k x 4c)
  if (tid < 384) {
    int k0 = 2*(tid >> 4), c0 = 4*(tid & 15);
    float acc[2][4] = {};
    #pragma unroll 4
    for (int m = 0; m < 48; m += 4) {
      float kv[2][4], tv[4][4];
      ld4(&SK_(k0+0,m), kv[0]); ld4(&SK_(k0+1,m), kv[1]);
      ld4(&TT_(c0+0,m), tv[0]); ld4(&TT_(c0+1,m), tv[1]);
      ld4(&TT_(c0+2,m), tv[2]); ld4(&TT_(c0+3,m), tv[3]);
      #pragma unroll
      for (int r = 0; r < 2; ++r)
        #pragma unroll
        for (int q = 0; q < 4; ++q)
          #pragma unroll
          for (int s = 0; s < 4; ++s)
            acc[r][q] += kv[r][s] * tv[q][s];
    }
    #pragma unroll
    for (int r = 0; r < 2; ++r)
      #pragma unroll
      for (int q = 0; q < 4; ++q) {
        int k = k0 + r, c = c0 + q;
        float v = acc[r][q];
        sR2[k*96 + c] = v;
        Bg[c*112 + 64 + k] = v;       // Bmat[:,64:] = R2^T
      }
  }
  // ---- R2 cols>=64 (selection from Ki) -- 1536 tasks, grid-stride
  #pragma unroll 1
  for (int t = tid; t < 48*32; t += 512) {
    int k = t >> 5, j = t & 31;
    float v = SK_(k, 16 + j);
    sR2[k*96 + 64 + j] = v;
    Bg[(64 + j)*112 + 64 + k] = v;
  }
  __syncthreads();

  // ---- P heavy rows (i<64): P = S_diag - T*R2  (1 row x 4 cols, 1536 tasks)
  #pragma unroll 1
  for (int t = tid; t < 1536; t += 512) {
    int i = t / 24, jq = t - (t / 24) * 24;
    int j0 = jq * 4;
    float acc[4];
    #pragma unroll
    for (int q = 0; q < 4; ++q)
      acc[q] = (j0 < 64) ? SM_(i, j0 + q) : 0.0f;
    #pragma unroll 4
    for (int m = 0; m < 48; m += 4) {
      float tv[4], rv[4][4];
      ld4(&TT_(i, m), tv);
      ld4(&sR2[(m+0)*96 + j0], rv[0]);
      ld4(&sR2[(m+1)*96 + j0], rv[1]);
      ld4(&sR2[(m+2)*96 + j0], rv[2]);
      ld4(&sR2[(m+3)*96 + j0], rv[3]);
      #pragma unroll
      for (int q = 0; q < 4; ++q)
        #pragma unroll
        for (int s = 0; s < 4; ++s)
          acc[q] -= tv[s] * rv[s][q];
    }
    #pragma unroll
    for (int q = 0; q < 4; ++q) {
      int j = j0 + q;
      float v = acc[q];
      Pg[i*96 + j] = v;
      if (j0 < 64) Bg[i*112 + j] = -v;     // Bmat[:,:64] = -P[:,:64]
    }
  }
  // ---- P rows >= 64: P[64+a][j] = (64+a==j) - R2[16+a][j]
  #pragma unroll 1
  for (int t = tid; t < 32*96; t += 512) {
    int a = t / 96, j = t - (t / 96) * 96;
    float v = ((64 + a) == j ? 1.0f : 0.0f) - sR2[(16 + a)*96 + j];
    Pg[(64 + a)*96 + j] = v;
    if (j < 64) Bg[(64 + a)*112 + j] = -v;
  }
#undef SM_
#undef TT_
#undef SK_
#undef JX_
}

// ---------------------------------------------------------------- kernel B
#define EB 16   // elements per block; grid = 256 blocks x 384 threads (1/CU)

__global__ __launch_bounds__(384, 1) void iter_kernel(
    const float* __restrict__ xg, const float* __restrict__ pg,
    const float* __restrict__ Pg, const float* __restrict__ Bg,
    float* __restrict__ outg)
{
  // Thread (eg 0..7, rg 0..47): P rows {2rg, 2rg+1} in registers (192 VGPR),
  // elements {2eg, 2eg+1}. x double-buffered in LDS; x-reads 1-ahead
  // prefetched so LDS latency hides under the 16 FMAs per kq.
  __shared__ float sX[2][EB][100];
  __shared__ float sPar[EB][112];

  const int tid = threadIdx.x;          // 0..383
  const int gbase = blockIdx.x * EB;
  const int eg = tid / 48;              // 0..7
  const int rg = tid - 48 * eg;         // 0..47
  const int e0 = 2 * eg, r0 = 2 * rg;

  // stage x (384 quads, exactly 1/thread) and parms (448 quads)
  const float4* X4 = (const float4*)xg;
  {
    int e = tid / 24, kc = tid - 24 * (tid / 24);
    *(float4*)&sX[0][e][kc*4] = X4[gbase*24 + tid];
  }
  const float4* Par4 = (const float4*)pg;
  for (int t = tid; t < EB*28; t += 384) {
    int e = t / 28, jc = t - 28 * e;
    *(float4*)&sPar[e][jc*4] = Par4[gbase*28 + t];
  }

  // my 2 P rows -> registers (issued before barrier; lands under c-phase)
  float4 pA[24], pB[24];
  const float4* P4 = (const float4*)Pg;
  #pragma unroll
  for (int kq = 0; kq < 24; ++kq) pA[kq] = P4[r0*24 + kq];
  #pragma unroll
  for (int kq = 0; kq < 24; ++kq) pB[kq] = P4[(r0+1)*24 + kq];

  __syncthreads();

  // c = Bmat(rows r0,r0+1) @ parms(elems e0,e0+1)
  float c00 = 0.f, c01 = 0.f, c10 = 0.f, c11 = 0.f;
  {
    const float4* B4 = (const float4*)Bg;
    #pragma unroll 4
    for (int jc = 0; jc < 28; ++jc) {
      float4 b0 = B4[r0*28 + jc];
      float4 b1 = B4[(r0+1)*28 + jc];
      float4 q0 = *(const float4*)&sPar[e0    ][jc*4];
      float4 q1 = *(const float4*)&sPar[e0 + 1][jc*4];
      c00 += dot4f(b0, q0); c01 += dot4f(b0, q1);
      c10 += dot4f(b1, q0); c11 += dot4f(b1, q1);
    }
  }

  const float lo = (r0 < 64) ? -1000.0f : 0.0f;
  const float* curb = &sX[0][0][0];
  float* nxtb = &sX[1][0][0];

  #pragma unroll 1
  for (int it = 0; it < 10; ++it) {
    float a00 = c00, a01 = c01, a10 = c10, a11 = c11;
    const float* x0p = curb + e0 * 100;
    const float* x1p = x0p + 100;
    float4 x0 = *(const float4*)(x0p);
    float4 x1 = *(const float4*)(x1p);
    #pragma unroll
    for (int kq = 0; kq < 24; ++kq) {
      float4 nx0, nx1;
      if (kq < 23) {                       // prefetch next quad pair
        nx0 = *(const float4*)(x0p + (kq+1)*4);
        nx1 = *(const float4*)(x1p + (kq+1)*4);
      }
      a00 += dot4f(pA[kq], x0); a01 += dot4f(pA[kq], x1);
      a10 += dot4f(pB[kq], x0); a11 += dot4f(pB[kq], x1);
      if (kq < 23) { x0 = nx0; x1 = nx1; }
    }
    if (it < 9) {
      float2 xo0 = *(const float2*)(x0p + r0);
      float2 xo1 = *(const float2*)(x1p + r0);
      float z00 = fminf(fmaxf(2.f*a00 - xo0.x, lo), 1000.f);
      float z10 = fminf(fmaxf(2.f*a10 - xo0.y, lo), 1000.f);
      float z01 = fminf(fmaxf(2.f*a01 - xo1.x, lo), 1000.f);
      float z11 = fminf(fmaxf(2.f*a11 - xo1.y, lo), 1000.f);
      *(float2*)(nxtb + e0*100 + r0) =
          make_float2(xo0.x + z00 - a00, xo0.y + z10 - a10);
      *(float2*)(nxtb + (e0+1)*100 + r0) =
          make_float2(xo1.x + z01 - a01, xo1.y + z11 - a11);
      __syncthreads();
      float* t = (float*)curb; curb = nxtb; nxtb = t;
    } else {
      if (r0 < 64) {
        *(float2*)&outg[(gbase + e0    )*64 + r0] = make_float2(a00, a10);
        *(float2*)&outg[(gbase + e0 + 1)*64 + r0] = make_float2(a01, a11);
      }
    }
  }
}

// ---------------------------------------------------------------- launch
extern "C" void kernel_launch(void* const* d_in, const int* in_sizes, int n_in,
                              void* d_out, int out_size, void* d_ws, size_t ws_size,
                              hipStream_t stream) {
  const float* x     = (const float*)d_in[0];   // (4096, 96)
  const float* parms = (const float*)d_in[1];   // (4096, 112)
  const float* Qg    = (const float*)d_in[2];   // (64, 64)
  const float* Ag    = (const float*)d_in[3];   // (16, 64)
  const float* Gg    = (const float*)d_in[4];   // (32, 64)
  float* out = (float*)d_out;                   // (4096, 64)

  float* ws  = (float*)d_ws;
  float* Pg  = ws;               // 96*96  = 9216
  float* Bg  = ws + 9216;        // 96*112 = 10752

  prep_kernel<<<1, 512, 0, stream>>>(Qg, Ag, Gg, Pg, Bg);
  iter_kernel<<<4096 / EB, 384, 0, stream>>>(x, parms, Pg, Bg, out);
}

// Round 11
// 86.276 us; speedup vs baseline: 1.4070x; 1.4070x over previous
//
#include <hip/hip_runtime.h>

// DR splitting solver. BATCH=4096, N=96 (64 x + 32 s), M=48 (16 eq + 32 ineq).
// JF and Hessian are batch-independent => prox_g1 is an affine map y = P x + Bmat p.
//   S=(I+Q)^{-1}; T=S Jx^T; K2=Jx T+diag(0,I32); R2=K2^{-1}[T^T|E];
//   P=diag(S,I)-[T;E^T]R2; Bmat=[-P[:,:64] | R2^T]
// Iterate 10x: y=Px+c; x += clamp(2y-x,l,u)-y; out=y[:64].
//
// Round-10 lesson: any prep block >256 threads gets a starved VGPR budget
// (3rd occurrence) -> spills on the serial GJ path. prep pinned to the round-9
// 256-thread shape (measured 42us, VGPR 104, no spill). iter: grid was exactly
// 1 block/CU (256 blocks, 6 waves, barrier-locked) -> EB=8/192thr/512 blocks
// gives 2 independent blocks per CU to interleave stalls.

__device__ __forceinline__ float dot4f(float4 a, float4 b) {
  return a.x*b.x + a.y*b.y + a.z*b.z + a.w*b.w;
}
__device__ __forceinline__ void ld4(const float* p, float* d) {
  float4 v = *(const float4*)p;
  d[0] = v.x; d[1] = v.y; d[2] = v.z; d[3] = v.w;
}
__device__ __forceinline__ void st4(float* p, const float* s) {
  *(float4*)p = make_float4(s[0], s[1], s[2], s[3]);
}
__device__ __forceinline__ float fastrcp(float x) {
  float r = __builtin_amdgcn_rcpf(x);
  return r * (2.0f - x * r);     // 1 Newton step: ~1e-7 rel
}
// W = A*B (4x4)
__device__ __forceinline__ void mm4(float W[4][4], const float A[4][4], const float B[4][4]) {
  #pragma unroll
  for (int r = 0; r < 4; ++r)
    #pragma unroll
    for (int q = 0; q < 4; ++q) {
      float s = A[r][0]*B[0][q];
      #pragma unroll
      for (int k = 1; k < 4; ++k) s += A[r][k]*B[k][q];
      W[r][q] = s;
    }
}
// in-place 4x4 inverse by GJ, no pivoting (SPD principal blocks)
__device__ __forceinline__ void inv4(float D[4][4]) {
  #pragma unroll
  for (int p = 0; p < 4; ++p) {
    float pi = fastrcp(D[p][p]);
    D[p][p] = pi;
    #pragma unroll
    for (int q = 0; q < 4; ++q) if (q != p) D[p][q] *= pi;
    #pragma unroll
    for (int i = 0; i < 4; ++i) if (i != p) {
      float f = D[i][p];
      #pragma unroll
      for (int q = 0; q < 4; ++q) if (q != p) D[i][q] -= f * D[p][q];
      D[i][p] = -f * pi;
    }
  }
}

// one double-buffered block-GJ step, stride 68 (64x64), all 256 threads
__device__ __forceinline__ void gj_step64(const float* __restrict__ src,
                                          float* __restrict__ dst,
                                          int b, int ig, int jg) {
  float D[4][4], C[4][4], R[4][4], T4[4][4], W[4][4];
  #pragma unroll
  for (int r = 0; r < 4; ++r) {
    ld4(&src[(4*b + r)*68 + 4*b],  D[r]);
    ld4(&src[(4*ig + r)*68 + 4*b], C[r]);
    ld4(&src[(4*b + r)*68 + 4*jg], R[r]);
    ld4(&src[(4*ig + r)*68 + 4*jg], T4[r]);
  }
  inv4(D);
  if (ig == b) {
    if (jg == b) {
      #pragma unroll
      for (int r = 0; r < 4; ++r)
        #pragma unroll
        for (int q = 0; q < 4; ++q) W[r][q] = D[r][q];
    } else {
      mm4(W, D, R);
    }
  } else {
    float E[4][4];
    mm4(E, C, D);
    if (jg == b) {
      #pragma unroll
      for (int r = 0; r < 4; ++r)
        #pragma unroll
        for (int q = 0; q < 4; ++q) W[r][q] = -E[r][q];
    } else {
      #pragma unroll
      for (int r = 0; r < 4; ++r)
        #pragma unroll
        for (int q = 0; q < 4; ++q) {
          float s = T4[r][q];
          #pragma unroll
          for (int k = 0; k < 4; ++k) s -= E[r][k] * R[k][q];
          W[r][q] = s;
        }
    }
  }
  #pragma unroll
  for (int r = 0; r < 4; ++r) st4(&dst[(4*ig + r)*68 + 4*jg], W[r]);
  __syncthreads();
}

// one double-buffered block-GJ step, stride 52 (48x48), threads 0..143 active
__device__ __forceinline__ void gj_step48(const float* __restrict__ src,
                                          float* __restrict__ dst,
                                          int b, int tid) {
  const bool act = tid < 144;
  const int ig = tid / 12, jg = tid - (tid / 12) * 12;
  float D[4][4], C[4][4], R[4][4], T4[4][4], W[4][4];
  if (act) {
    #pragma unroll
    for (int r = 0; r < 4; ++r) {
      ld4(&src[(4*b + r)*52 + 4*b],  D[r]);
      ld4(&src[(4*ig + r)*52 + 4*b], C[r]);
      ld4(&src[(4*b + r)*52 + 4*jg], R[r]);
      ld4(&src[(4*ig + r)*52 + 4*jg], T4[r]);
    }
    inv4(D);
    if (ig == b) {
      if (jg == b) {
        #pragma unroll
        for (int r = 0; r < 4; ++r)
          #pragma unroll
          for (int q = 0; q < 4; ++q) W[r][q] = D[r][q];
      } else {
        mm4(W, D, R);
      }
    } else {
      float E[4][4];
      mm4(E, C, D);
      if (jg == b) {
        #pragma unroll
        for (int r = 0; r < 4; ++r)
          #pragma unroll
          for (int q = 0; q < 4; ++q) W[r][q] = -E[r][q];
      } else {
        #pragma unroll
        for (int r = 0; r < 4; ++r)
          #pragma unroll
          for (int q = 0; q < 4; ++q) {
            float s = T4[r][q];
            #pragma unroll
            for (int k = 0; k < 4; ++k) s -= E[r][k] * R[k][q];
            W[r][q] = s;
          }
      }
    }
    #pragma unroll
    for (int r = 0; r < 4; ++r) st4(&dst[(4*ig + r)*52 + 4*jg], W[r]);
  }
  __syncthreads();
}

// ---------------------------------------------------------------- kernel A
__global__ __launch_bounds__(256, 1) void prep_kernel(
    const float* __restrict__ Qg, const float* __restrict__ Ag,
    const float* __restrict__ Gg,
    float* __restrict__ Pg, float* __restrict__ Bg)
{
  // floats: 4352 + 4352 + 2496 + 4608 = 15808 = 63232 B
  __shared__ float sMa[64*68];   // M1 ping  -> S (after 16 steps)
  __shared__ float sMb[64*68];   // M1 pong  -> T (64x48, stride 48)
  __shared__ float sK [48*52];   // K2 ping  -> Ki
  __shared__ float sR2[48*96];   // Jx (s68) -> K2 pong (s52) -> R2 (s96)

#define SM_(i,j) sMa[(i)*68+(j)]
#define TT_(i,j) sMb[(i)*48+(j)]
#define SK_(i,j) sK[(i)*52+(j)]
#define JX_(a,k) sR2[(a)*68+(k)]

  const int tid = threadIdx.x;
  const int ig = tid >> 4, jg = tid & 15;

  // ---- stage Jx = [A;G] (48x64, stride 68) and M1 = Q + I
  {
    const float4* A4 = (const float4*)Ag;          // 256 quads
    const float4* G4 = (const float4*)Gg;          // 512 quads
    {
      int t = tid;
      int a = t >> 4, kc = t & 15;
      st4(&JX_(a, kc*4), (const float*)&A4[t]);
    }
    for (int t = tid; t < 512; t += 256) {
      int a = t >> 4, kc = t & 15;
      st4(&JX_(16 + a, kc*4), (const float*)&G4[t]);
    }
    const float4* Q4 = (const float4*)Qg;          // 1024 quads
    for (int t = tid; t < 1024; t += 256) {
      int i = t >> 4, kc = t & 15;
      st4(&SM_(i, kc*4), (const float*)&Q4[t]);
    }
  }
  __syncthreads();
  if (tid < 64) SM_(tid, tid) += 1.0f;
  __syncthreads();

  // ---- block-GJ 64 (dbuf, 1 barrier/step, 16 steps) -> S in sMa
  #pragma unroll 1
  for (int p = 0; p < 8; ++p) {
    gj_step64(sMa, sMb, 2*p,     ig, jg);
    gj_step64(sMb, sMa, 2*p + 1, ig, jg);
  }

  // ---- T = S Jx^T : 4x3 register tile/thread (16 ig x 16 jg covers 64x48)
  {
    const int i0 = 4*ig, j0 = 3*jg;
    float acc[4][3] = {};
    #pragma unroll 4
    for (int kq = 0; kq < 16; ++kq) {
      float sv[4][4], jv[3][4];
      ld4(&SM_(i0+0, kq*4), sv[0]); ld4(&SM_(i0+1, kq*4), sv[1]);
      ld4(&SM_(i0+2, kq*4), sv[2]); ld4(&SM_(i0+3, kq*4), sv[3]);
      ld4(&JX_(j0+0, kq*4), jv[0]); ld4(&JX_(j0+1, kq*4), jv[1]);
      ld4(&JX_(j0+2, kq*4), jv[2]);
      #pragma unroll
      for (int r = 0; r < 4; ++r)
        #pragma unroll
        for (int c = 0; c < 3; ++c)
          #pragma unroll
          for (int s = 0; s < 4; ++s)
            acc[r][c] += sv[r][s] * jv[c][s];
    }
    __syncthreads();   // SM/JX reads done before TT writes to sMb pong
    #pragma unroll
    for (int r = 0; r < 4; ++r)
      #pragma unroll
      for (int c = 0; c < 3; ++c)
        TT_(i0+r, j0+c) = acc[r][c];
  }
  __syncthreads();

  // ---- K2 = Jx T + diag(0,I32)  (192 threads, 3x4 tiles)
  if (tid < 192) {
    int ag = tid / 12, bg = tid - ag*12;
    int a0 = ag*3, b0 = bg*4;
    float acc[3][4] = {};
    #pragma unroll 4
    for (int k = 0; k < 64; ++k) {
      float4 tb = *(const float4*)&TT_(k,b0);
      #pragma unroll
      for (int r = 0; r < 3; ++r) {
        float jv = JX_(a0 + r, k);
        acc[r][0] += jv*tb.x; acc[r][1] += jv*tb.y;
        acc[r][2] += jv*tb.z; acc[r][3] += jv*tb.w;
      }
    }
    #pragma unroll
    for (int r = 0; r < 3; ++r)
      #pragma unroll
      for (int q = 0; q < 4; ++q) {
        int a = a0 + r, b = b0 + q;
        SK_(a,b) = acc[r][q] + ((a == b && a >= 16) ? 1.0f : 0.0f);
      }
  }
  __syncthreads();

  // ---- block-GJ 48 (dbuf; pong overlays dead Jx region) -> Ki in sK
  {
    float* KP = sR2;   // 48*52 = 2496 <= 4608
    #pragma unroll 1
    for (int p = 0; p < 6; ++p) {
      gj_step48(sK, KP, 2*p,     tid);
      gj_step48(KP, sK, 2*p + 1, tid);
    }
  }
  // KP / JX dead; sR2 region becomes R2 (stride 96).

  // ---- R2 cols<64: R2[k][c] = sum_m Ki[k][m]*T[c][m]  (3k x 4c tiles)
  {
    int kg = tid >> 4, cg = tid & 15;
    int k0 = kg*3, c0 = cg*4;
    float acc[3][4] = {};
    #pragma unroll 4
    for (int m = 0; m < 48; m += 4) {
      float kv[3][4], tv[4][4];
      ld4(&SK_(k0+0,m), kv[0]); ld4(&SK_(k0+1,m), kv[1]); ld4(&SK_(k0+2,m), kv[2]);
      ld4(&TT_(c0+0,m), tv[0]); ld4(&TT_(c0+1,m), tv[1]);
      ld4(&TT_(c0+2,m), tv[2]); ld4(&TT_(c0+3,m), tv[3]);
      #pragma unroll
      for (int r = 0; r < 3; ++r)
        #pragma unroll
        for (int q = 0; q < 4; ++q)
          #pragma unroll
          for (int s = 0; s < 4; ++s)
            acc[r][q] += kv[r][s] * tv[q][s];
    }
    #pragma unroll
    for (int r = 0; r < 3; ++r)
      #pragma unroll
      for (int q = 0; q < 4; ++q) {
        int k = k0 + r, c = c0 + q;
        float v = acc[r][q];
        sR2[k*96 + c] = v;
        Bg[c*112 + 64 + k] = v;       // Bmat[:,64:] = R2^T
      }
  }
  // R2 cols>=64 (selection from Ki)
  #pragma unroll 1
  for (int t = tid; t < 48*32; t += 256) {
    int k = t >> 5, j = t & 31;
    float v = SK_(k, 16 + j);
    sR2[k*96 + 64 + j] = v;
    Bg[(64 + j)*112 + 64 + k] = v;
  }
  __syncthreads();

  // ---- P heavy rows (i<64): P = S_diag - T*R2  (16 ig x 24 jc tasks)
  #pragma unroll 1
  for (int task = tid; task < 384; task += 256) {
    int tg = task / 24, jc = task - tg*24;
    int i0 = tg*4, j0 = jc*4;
    float acc[4][4];
    #pragma unroll
    for (int r = 0; r < 4; ++r)
      #pragma unroll
      for (int q = 0; q < 4; ++q)
        acc[r][q] = (j0 < 64) ? SM_(i0+r, j0+q) : 0.0f;
    #pragma unroll 4
    for (int m = 0; m < 48; m += 4) {
      float tv[4][4], rv[4][4];
      ld4(&TT_(i0+0,m), tv[0]); ld4(&TT_(i0+1,m), tv[1]);
      ld4(&TT_(i0+2,m), tv[2]); ld4(&TT_(i0+3,m), tv[3]);
      ld4(&sR2[(m+0)*96 + j0], rv[0]);
      ld4(&sR2[(m+1)*96 + j0], rv[1]);
      ld4(&sR2[(m+2)*96 + j0], rv[2]);
      ld4(&sR2[(m+3)*96 + j0], rv[3]);
      #pragma unroll
      for (int r = 0; r < 4; ++r)
        #pragma unroll
        for (int q = 0; q < 4; ++q)
          #pragma unroll
          for (int s = 0; s < 4; ++s)
            acc[r][q] -= tv[r][s] * rv[s][q];
    }
    #pragma unroll
    for (int r = 0; r < 4; ++r)
      #pragma unroll
      for (int q = 0; q < 4; ++q) {
        int i = i0 + r, j = j0 + q;
        float v = acc[r][q];
        Pg[i*96 + j] = v;
        if (j0 < 64) Bg[i*112 + j] = -v;   // Bmat[:,:64] = -P[:,:64]
      }
  }
  // ---- P rows >= 64: P[64+a][j] = (64+a==j) - R2[16+a][j]
  #pragma unroll 1
  for (int t = tid; t < 32*96; t += 256) {
    int a = t / 96, j = t - (t / 96) * 96;
    float v = ((64 + a) == j ? 1.0f : 0.0f) - sR2[(16 + a)*96 + j];
    Pg[(64 + a)*96 + j] = v;
    if (j < 64) Bg[(64 + a)*112 + j] = -v;
  }
#undef SM_
#undef TT_
#undef SK_
#undef JX_
}

// ---------------------------------------------------------------- kernel B
#define EB 8   // elements per block; grid = 512 blocks x 192 threads (2/CU)

__global__ __launch_bounds__(192, 1) void iter_kernel(
    const float* __restrict__ xg, const float* __restrict__ pg,
    const float* __restrict__ Pg, const float* __restrict__ Bg,
    float* __restrict__ outg)
{
  // Thread (eg 0..3, rg 0..47): P rows {2rg, 2rg+1} in registers (192 VGPR),
  // elements {2eg, 2eg+1}. 512 blocks -> 2 independent blocks/CU so barrier
  // and LDS-latency stalls of one block hide under the other.
  __shared__ float sX[2][EB][100];
  __shared__ float sPar[EB][112];

  const int tid = threadIdx.x;          // 0..191
  const int gbase = blockIdx.x * EB;
  const int eg = tid / 48;              // 0..3
  const int rg = tid - 48 * eg;         // 0..47
  const int e0 = 2 * eg, r0 = 2 * rg;

  // stage x (192 quads, exactly 1/thread) and parms (224 quads)
  const float4* X4 = (const float4*)xg;
  {
    int e = tid / 24, kc = tid - 24 * (tid / 24);
    *(float4*)&sX[0][e][kc*4] = X4[gbase*24 + tid];
  }
  const float4* Par4 = (const float4*)pg;
  for (int t = tid; t < EB*28; t += 192) {
    int e = t / 28, jc = t - 28 * e;
    *(float4*)&sPar[e][jc*4] = Par4[gbase*28 + t];
  }

  // my 2 P rows -> registers (issued before barrier; lands under c-phase)
  float4 pA[24], pB[24];
  const float4* P4 = (const float4*)Pg;
  #pragma unroll
  for (int kq = 0; kq < 24; ++kq) pA[kq] = P4[r0*24 + kq];
  #pragma unroll
  for (int kq = 0; kq < 24; ++kq) pB[kq] = P4[(r0+1)*24 + kq];

  __syncthreads();

  // c = Bmat(rows r0,r0+1) @ parms(elems e0,e0+1)
  float c00 = 0.f, c01 = 0.f, c10 = 0.f, c11 = 0.f;
  {
    const float4* B4 = (const float4*)Bg;
    #pragma unroll 4
    for (int jc = 0; jc < 28; ++jc) {
      float4 b0 = B4[r0*28 + jc];
      float4 b1 = B4[(r0+1)*28 + jc];
      float4 q0 = *(const float4*)&sPar[e0    ][jc*4];
      float4 q1 = *(const float4*)&sPar[e0 + 1][jc*4];
      c00 += dot4f(b0, q0); c01 += dot4f(b0, q1);
      c10 += dot4f(b1, q0); c11 += dot4f(b1, q1);
    }
  }

  const float lo = (r0 < 64) ? -1000.0f : 0.0f;
  const float* curb = &sX[0][0][0];
  float* nxtb = &sX[1][0][0];

  #pragma unroll 1
  for (int it = 0; it < 10; ++it) {
    float a00 = c00, a01 = c01, a10 = c10, a11 = c11;
    const float* x0p = curb + e0 * 100;
    const float* x1p = x0p + 100;
    float4 x0 = *(const float4*)(x0p);
    float4 x1 = *(const float4*)(x1p);
    #pragma unroll
    for (int kq = 0; kq < 24; ++kq) {
      float4 nx0, nx1;
      if (kq < 23) {                       // prefetch next quad pair
        nx0 = *(const float4*)(x0p + (kq+1)*4);
        nx1 = *(const float4*)(x1p + (kq+1)*4);
      }
      a00 += dot4f(pA[kq], x0); a01 += dot4f(pA[kq], x1);
      a10 += dot4f(pB[kq], x0); a11 += dot4f(pB[kq], x1);
      if (kq < 23) { x0 = nx0; x1 = nx1; }
    }
    if (it < 9) {
      float2 xo0 = *(const float2*)(x0p + r0);
      float2 xo1 = *(const float2*)(x1p + r0);
      float z00 = fminf(fmaxf(2.f*a00 - xo0.x, lo), 1000.f);
      float z10 = fminf(fmaxf(2.f*a10 - xo0.y, lo), 1000.f);
      float z01 = fminf(fmaxf(2.f*a01 - xo1.x, lo), 1000.f);
      float z11 = fminf(fmaxf(2.f*a11 - xo1.y, lo), 1000.f);
      *(float2*)(nxtb + e0*100 + r0) =
          make_float2(xo0.x + z00 - a00, xo0.y + z10 - a10);
      *(float2*)(nxtb + (e0+1)*100 + r0) =
          make_float2(xo1.x + z01 - a01, xo1.y + z11 - a11);
      __syncthreads();
      float* t = (float*)curb; curb = nxtb; nxtb = t;
    } else {
      if (r0 < 64) {
        *(float2*)&outg[(gbase + e0    )*64 + r0] = make_float2(a00, a10);
        *(float2*)&outg[(gbase + e0 + 1)*64 + r0] = make_float2(a01, a11);
      }
    }
  }
}

// ---------------------------------------------------------------- launch
extern "C" void kernel_launch(void* const* d_in, const int* in_sizes, int n_in,
                              void* d_out, int out_size, void* d_ws, size_t ws_size,
                              hipStream_t stream) {
  const float* x     = (const float*)d_in[0];   // (4096, 96)
  const float* parms = (const float*)d_in[1];   // (4096, 112)
  const float* Qg    = (const float*)d_in[2];   // (64, 64)
  const float* Ag    = (const float*)d_in[3];   // (16, 64)
  const float* Gg    = (const float*)d_in[4];   // (32, 64)
  float* out = (float*)d_out;                   // (4096, 64)

  float* ws  = (float*)d_ws;
  float* Pg  = ws;               // 96*96  = 9216
  float* Bg  = ws + 9216;        // 96*112 = 10752

  prep_kernel<<<1, 256, 0, stream>>>(Qg, Ag, Gg, Pg, Bg);
  iter_kernel<<<4096 / EB, 192, 0, stream>>>(x, parms, Pg, Bg, out);
}

// Round 12
// 78.790 us; speedup vs baseline: 1.5407x; 1.0950x over previous
//
#include <hip/hip_runtime.h>

// DR splitting solver. BATCH=4096, N=96 (64 x + 32 s), M=48 (16 eq + 32 ineq).
// JF and Hessian are batch-independent => prox_g1 is an affine map y = P x + Bmat p.
//   S=(I+Q)^{-1}; T=S Jx^T; K2=Jx T+diag(0,I32); R2=K2^{-1}[T^T|E];
//   P=diag(S,I)-[T;E^T]R2; Bmat=[-P[:,:64] | R2^T]
// Iterate 10x: y=Px+c; x += clamp(2y-x,l,u)-y; out=y[:64].
//
// Round-11 lesson: iter's VGPR_Count=132 < the 192 needed for pA/pB -> compiler
// spills P rows to scratch (FETCH 2MB/dispatch), and EB=8 doubled thread count
// -> doubled spill traffic (47us). Round-12: revert iter to EB=16/384thr (best
// measured) + amdgpu_waves_per_eu(1,2) to raise the VGPR ceiling so P can be
// register-resident. prep = round-9 proven shape (42us, VGPR 104), untouched.

__device__ __forceinline__ float dot4f(float4 a, float4 b) {
  return a.x*b.x + a.y*b.y + a.z*b.z + a.w*b.w;
}
__device__ __forceinline__ void ld4(const float* p, float* d) {
  float4 v = *(const float4*)p;
  d[0] = v.x; d[1] = v.y; d[2] = v.z; d[3] = v.w;
}
__device__ __forceinline__ void st4(float* p, const float* s) {
  *(float4*)p = make_float4(s[0], s[1], s[2], s[3]);
}
__device__ __forceinline__ float fastrcp(float x) {
  float r = __builtin_amdgcn_rcpf(x);
  return r * (2.0f - x * r);     // 1 Newton step: ~1e-7 rel
}
// W = A*B (4x4)
__device__ __forceinline__ void mm4(float W[4][4], const float A[4][4], const float B[4][4]) {
  #pragma unroll
  for (int r = 0; r < 4; ++r)
    #pragma unroll
    for (int q = 0; q < 4; ++q) {
      float s = A[r][0]*B[0][q];
      #pragma unroll
      for (int k = 1; k < 4; ++k) s += A[r][k]*B[k][q];
      W[r][q] = s;
    }
}
// in-place 4x4 inverse by GJ, no pivoting (SPD principal blocks)
__device__ __forceinline__ void inv4(float D[4][4]) {
  #pragma unroll
  for (int p = 0; p < 4; ++p) {
    float pi = fastrcp(D[p][p]);
    D[p][p] = pi;
    #pragma unroll
    for (int q = 0; q < 4; ++q) if (q != p) D[p][q] *= pi;
    #pragma unroll
    for (int i = 0; i < 4; ++i) if (i != p) {
      float f = D[i][p];
      #pragma unroll
      for (int q = 0; q < 4; ++q) if (q != p) D[i][q] -= f * D[p][q];
      D[i][p] = -f * pi;
    }
  }
}

// one double-buffered block-GJ step, stride 68 (64x64), all 256 threads
__device__ __forceinline__ void gj_step64(const float* __restrict__ src,
                                          float* __restrict__ dst,
                                          int b, int ig, int jg) {
  float D[4][4], C[4][4], R[4][4], T4[4][4], W[4][4];
  #pragma unroll
  for (int r = 0; r < 4; ++r) {
    ld4(&src[(4*b + r)*68 + 4*b],  D[r]);
    ld4(&src[(4*ig + r)*68 + 4*b], C[r]);
    ld4(&src[(4*b + r)*68 + 4*jg], R[r]);
    ld4(&src[(4*ig + r)*68 + 4*jg], T4[r]);
  }
  inv4(D);
  if (ig == b) {
    if (jg == b) {
      #pragma unroll
      for (int r = 0; r < 4; ++r)
        #pragma unroll
        for (int q = 0; q < 4; ++q) W[r][q] = D[r][q];
    } else {
      mm4(W, D, R);
    }
  } else {
    float E[4][4];
    mm4(E, C, D);
    if (jg == b) {
      #pragma unroll
      for (int r = 0; r < 4; ++r)
        #pragma unroll
        for (int q = 0; q < 4; ++q) W[r][q] = -E[r][q];
    } else {
      #pragma unroll
      for (int r = 0; r < 4; ++r)
        #pragma unroll
        for (int q = 0; q < 4; ++q) {
          float s = T4[r][q];
          #pragma unroll
          for (int k = 0; k < 4; ++k) s -= E[r][k] * R[k][q];
          W[r][q] = s;
        }
    }
  }
  #pragma unroll
  for (int r = 0; r < 4; ++r) st4(&dst[(4*ig + r)*68 + 4*jg], W[r]);
  __syncthreads();
}

// one double-buffered block-GJ step, stride 52 (48x48), threads 0..143 active
__device__ __forceinline__ void gj_step48(const float* __restrict__ src,
                                          float* __restrict__ dst,
                                          int b, int tid) {
  const bool act = tid < 144;
  const int ig = tid / 12, jg = tid - (tid / 12) * 12;
  float D[4][4], C[4][4], R[4][4], T4[4][4], W[4][4];
  if (act) {
    #pragma unroll
    for (int r = 0; r < 4; ++r) {
      ld4(&src[(4*b + r)*52 + 4*b],  D[r]);
      ld4(&src[(4*ig + r)*52 + 4*b], C[r]);
      ld4(&src[(4*b + r)*52 + 4*jg], R[r]);
      ld4(&src[(4*ig + r)*52 + 4*jg], T4[r]);
    }
    inv4(D);
    if (ig == b) {
      if (jg == b) {
        #pragma unroll
        for (int r = 0; r < 4; ++r)
          #pragma unroll
          for (int q = 0; q < 4; ++q) W[r][q] = D[r][q];
      } else {
        mm4(W, D, R);
      }
    } else {
      float E[4][4];
      mm4(E, C, D);
      if (jg == b) {
        #pragma unroll
        for (int r = 0; r < 4; ++r)
          #pragma unroll
          for (int q = 0; q < 4; ++q) W[r][q] = -E[r][q];
      } else {
        #pragma unroll
        for (int r = 0; r < 4; ++r)
          #pragma unroll
          for (int q = 0; q < 4; ++q) {
            float s = T4[r][q];
            #pragma unroll
            for (int k = 0; k < 4; ++k) s -= E[r][k] * R[k][q];
            W[r][q] = s;
          }
      }
    }
    #pragma unroll
    for (int r = 0; r < 4; ++r) st4(&dst[(4*ig + r)*52 + 4*jg], W[r]);
  }
  __syncthreads();
}

// ---------------------------------------------------------------- kernel A
__global__ __launch_bounds__(256, 1) void prep_kernel(
    const float* __restrict__ Qg, const float* __restrict__ Ag,
    const float* __restrict__ Gg,
    float* __restrict__ Pg, float* __restrict__ Bg)
{
  // floats: 4352 + 4352 + 2496 + 4608 = 15808 = 63232 B
  __shared__ float sMa[64*68];   // M1 ping  -> S (after 16 steps)
  __shared__ float sMb[64*68];   // M1 pong  -> T (64x48, stride 48)
  __shared__ float sK [48*52];   // K2 ping  -> Ki
  __shared__ float sR2[48*96];   // Jx (s68) -> K2 pong (s52) -> R2 (s96)

#define SM_(i,j) sMa[(i)*68+(j)]
#define TT_(i,j) sMb[(i)*48+(j)]
#define SK_(i,j) sK[(i)*52+(j)]
#define JX_(a,k) sR2[(a)*68+(k)]

  const int tid = threadIdx.x;
  const int ig = tid >> 4, jg = tid & 15;

  // ---- stage Jx = [A;G] (48x64, stride 68) and M1 = Q + I
  {
    const float4* A4 = (const float4*)Ag;          // 256 quads
    const float4* G4 = (const float4*)Gg;          // 512 quads
    {
      int t = tid;
      int a = t >> 4, kc = t & 15;
      st4(&JX_(a, kc*4), (const float*)&A4[t]);
    }
    for (int t = tid; t < 512; t += 256) {
      int a = t >> 4, kc = t & 15;
      st4(&JX_(16 + a, kc*4), (const float*)&G4[t]);
    }
    const float4* Q4 = (const float4*)Qg;          // 1024 quads
    for (int t = tid; t < 1024; t += 256) {
      int i = t >> 4, kc = t & 15;
      st4(&SM_(i, kc*4), (const float*)&Q4[t]);
    }
  }
  __syncthreads();
  if (tid < 64) SM_(tid, tid) += 1.0f;
  __syncthreads();

  // ---- block-GJ 64 (dbuf, 1 barrier/step, 16 steps) -> S in sMa
  #pragma unroll 1
  for (int p = 0; p < 8; ++p) {
    gj_step64(sMa, sMb, 2*p,     ig, jg);
    gj_step64(sMb, sMa, 2*p + 1, ig, jg);
  }

  // ---- T = S Jx^T : 4x3 register tile/thread (16 ig x 16 jg covers 64x48)
  {
    const int i0 = 4*ig, j0 = 3*jg;
    float acc[4][3] = {};
    #pragma unroll 4
    for (int kq = 0; kq < 16; ++kq) {
      float sv[4][4], jv[3][4];
      ld4(&SM_(i0+0, kq*4), sv[0]); ld4(&SM_(i0+1, kq*4), sv[1]);
      ld4(&SM_(i0+2, kq*4), sv[2]); ld4(&SM_(i0+3, kq*4), sv[3]);
      ld4(&JX_(j0+0, kq*4), jv[0]); ld4(&JX_(j0+1, kq*4), jv[1]);
      ld4(&JX_(j0+2, kq*4), jv[2]);
      #pragma unroll
      for (int r = 0; r < 4; ++r)
        #pragma unroll
        for (int c = 0; c < 3; ++c)
          #pragma unroll
          for (int s = 0; s < 4; ++s)
            acc[r][c] += sv[r][s] * jv[c][s];
    }
    __syncthreads();   // SM/JX reads done before TT writes to sMb pong
    #pragma unroll
    for (int r = 0; r < 4; ++r)
      #pragma unroll
      for (int c = 0; c < 3; ++c)
        TT_(i0+r, j0+c) = acc[r][c];
  }
  __syncthreads();

  // ---- K2 = Jx T + diag(0,I32)  (192 threads, 3x4 tiles)
  if (tid < 192) {
    int ag = tid / 12, bg = tid - ag*12;
    int a0 = ag*3, b0 = bg*4;
    float acc[3][4] = {};
    #pragma unroll 4
    for (int k = 0; k < 64; ++k) {
      float4 tb = *(const float4*)&TT_(k,b0);
      #pragma unroll
      for (int r = 0; r < 3; ++r) {
        float jv = JX_(a0 + r, k);
        acc[r][0] += jv*tb.x; acc[r][1] += jv*tb.y;
        acc[r][2] += jv*tb.z; acc[r][3] += jv*tb.w;
      }
    }
    #pragma unroll
    for (int r = 0; r < 3; ++r)
      #pragma unroll
      for (int q = 0; q < 4; ++q) {
        int a = a0 + r, b = b0 + q;
        SK_(a,b) = acc[r][q] + ((a == b && a >= 16) ? 1.0f : 0.0f);
      }
  }
  __syncthreads();

  // ---- block-GJ 48 (dbuf; pong overlays dead Jx region) -> Ki in sK
  {
    float* KP = sR2;   // 48*52 = 2496 <= 4608
    #pragma unroll 1
    for (int p = 0; p < 6; ++p) {
      gj_step48(sK, KP, 2*p,     tid);
      gj_step48(KP, sK, 2*p + 1, tid);
    }
  }
  // KP / JX dead; sR2 region becomes R2 (stride 96).

  // ---- R2 cols<64: R2[k][c] = sum_m Ki[k][m]*T[c][m]  (3k x 4c tiles)
  {
    int kg = tid >> 4, cg = tid & 15;
    int k0 = kg*3, c0 = cg*4;
    float acc[3][4] = {};
    #pragma unroll 4
    for (int m = 0; m < 48; m += 4) {
      float kv[3][4], tv[4][4];
      ld4(&SK_(k0+0,m), kv[0]); ld4(&SK_(k0+1,m), kv[1]); ld4(&SK_(k0+2,m), kv[2]);
      ld4(&TT_(c0+0,m), tv[0]); ld4(&TT_(c0+1,m), tv[1]);
      ld4(&TT_(c0+2,m), tv[2]); ld4(&TT_(c0+3,m), tv[3]);
      #pragma unroll
      for (int r = 0; r < 3; ++r)
        #pragma unroll
        for (int q = 0; q < 4; ++q)
          #pragma unroll
          for (int s = 0; s < 4; ++s)
            acc[r][q] += kv[r][s] * tv[q][s];
    }
    #pragma unroll
    for (int r = 0; r < 3; ++r)
      #pragma unroll
      for (int q = 0; q < 4; ++q) {
        int k = k0 + r, c = c0 + q;
        float v = acc[r][q];
        sR2[k*96 + c] = v;
        Bg[c*112 + 64 + k] = v;       // Bmat[:,64:] = R2^T
      }
  }
  // R2 cols>=64 (selection from Ki)
  #pragma unroll 1
  for (int t = tid; t < 48*32; t += 256) {
    int k = t >> 5, j = t & 31;
    float v = SK_(k, 16 + j);
    sR2[k*96 + 64 + j] = v;
    Bg[(64 + j)*112 + 64 + k] = v;
  }
  __syncthreads();

  // ---- P heavy rows (i<64): P = S_diag - T*R2  (16 ig x 24 jc tasks)
  #pragma unroll 1
  for (int task = tid; task < 384; task += 256) {
    int tg = task / 24, jc = task - tg*24;
    int i0 = tg*4, j0 = jc*4;
    float acc[4][4];
    #pragma unroll
    for (int r = 0; r < 4; ++r)
      #pragma unroll
      for (int q = 0; q < 4; ++q)
        acc[r][q] = (j0 < 64) ? SM_(i0+r, j0+q) : 0.0f;
    #pragma unroll 4
    for (int m = 0; m < 48; m += 4) {
      float tv[4][4], rv[4][4];
      ld4(&TT_(i0+0,m), tv[0]); ld4(&TT_(i0+1,m), tv[1]);
      ld4(&TT_(i0+2,m), tv[2]); ld4(&TT_(i0+3,m), tv[3]);
      ld4(&sR2[(m+0)*96 + j0], rv[0]);
      ld4(&sR2[(m+1)*96 + j0], rv[1]);
      ld4(&sR2[(m+2)*96 + j0], rv[2]);
      ld4(&sR2[(m+3)*96 + j0], rv[3]);
      #pragma unroll
      for (int r = 0; r < 4; ++r)
        #pragma unroll
        for (int q = 0; q < 4; ++q)
          #pragma unroll
          for (int s = 0; s < 4; ++s)
            acc[r][q] -= tv[r][s] * rv[s][q];
    }
    #pragma unroll
    for (int r = 0; r < 4; ++r)
      #pragma unroll
      for (int q = 0; q < 4; ++q) {
        int i = i0 + r, j = j0 + q;
        float v = acc[r][q];
        Pg[i*96 + j] = v;
        if (j0 < 64) Bg[i*112 + j] = -v;   // Bmat[:,:64] = -P[:,:64]
      }
  }
  // ---- P rows >= 64: P[64+a][j] = (64+a==j) - R2[16+a][j]
  #pragma unroll 1
  for (int t = tid; t < 32*96; t += 256) {
    int a = t / 96, j = t - (t / 96) * 96;
    float v = ((64 + a) == j ? 1.0f : 0.0f) - sR2[(16 + a)*96 + j];
    Pg[(64 + a)*96 + j] = v;
    if (j < 64) Bg[(64 + a)*112 + j] = -v;
  }
#undef SM_
#undef TT_
#undef SK_
#undef JX_
}

// ---------------------------------------------------------------- kernel B
#define EB 16   // elements per block; grid = 256 blocks x 384 threads

__global__ __launch_bounds__(384)
__attribute__((amdgpu_waves_per_eu(1, 2)))
void iter_kernel(
    const float* __restrict__ xg, const float* __restrict__ pg,
    const float* __restrict__ Pg, const float* __restrict__ Bg,
    float* __restrict__ outg)
{
  // Thread (eg 0..7, rg 0..47): P rows {2rg, 2rg+1} in registers (192 VGPR
  // wanted -- waves_per_eu(1,2) raises the allocator ceiling so they stay
  // resident), elements {2eg, 2eg+1}. x double-buffered in LDS with 1-ahead
  // prefetch in the dot loop.
  __shared__ float sX[2][EB][100];
  __shared__ float sPar[EB][112];

  const int tid = threadIdx.x;          // 0..383
  const int gbase = blockIdx.x * EB;
  const int eg = tid / 48;              // 0..7
  const int rg = tid - 48 * eg;         // 0..47
  const int e0 = 2 * eg, r0 = 2 * rg;

  // stage x (384 quads, exactly 1/thread) and parms (448 quads)
  const float4* X4 = (const float4*)xg;
  {
    int e = tid / 24, kc = tid - 24 * (tid / 24);
    *(float4*)&sX[0][e][kc*4] = X4[gbase*24 + tid];
  }
  const float4* Par4 = (const float4*)pg;
  for (int t = tid; t < EB*28; t += 384) {
    int e = t / 28, jc = t - 28 * e;
    *(float4*)&sPar[e][jc*4] = Par4[gbase*28 + t];
  }

  // my 2 P rows -> registers (issued before barrier; lands under c-phase)
  float4 pA[24], pB[24];
  const float4* P4 = (const float4*)Pg;
  #pragma unroll
  for (int kq = 0; kq < 24; ++kq) pA[kq] = P4[r0*24 + kq];
  #pragma unroll
  for (int kq = 0; kq < 24; ++kq) pB[kq] = P4[(r0+1)*24 + kq];

  __syncthreads();

  // c = Bmat(rows r0,r0+1) @ parms(elems e0,e0+1)
  float c00 = 0.f, c01 = 0.f, c10 = 0.f, c11 = 0.f;
  {
    const float4* B4 = (const float4*)Bg;
    #pragma unroll 4
    for (int jc = 0; jc < 28; ++jc) {
      float4 b0 = B4[r0*28 + jc];
      float4 b1 = B4[(r0+1)*28 + jc];
      float4 q0 = *(const float4*)&sPar[e0    ][jc*4];
      float4 q1 = *(const float4*)&sPar[e0 + 1][jc*4];
      c00 += dot4f(b0, q0); c01 += dot4f(b0, q1);
      c10 += dot4f(b1, q0); c11 += dot4f(b1, q1);
    }
  }

  const float lo = (r0 < 64) ? -1000.0f : 0.0f;
  const float* curb = &sX[0][0][0];
  float* nxtb = &sX[1][0][0];

  #pragma unroll 1
  for (int it = 0; it < 10; ++it) {
    float a00 = c00, a01 = c01, a10 = c10, a11 = c11;
    const float* x0p = curb + e0 * 100;
    const float* x1p = x0p + 100;
    float4 x0 = *(const float4*)(x0p);
    float4 x1 = *(const float4*)(x1p);
    #pragma unroll
    for (int kq = 0; kq < 24; ++kq) {
      float4 nx0, nx1;
      if (kq < 23) {                       // prefetch next quad pair
        nx0 = *(const float4*)(x0p + (kq+1)*4);
        nx1 = *(const float4*)(x1p + (kq+1)*4);
      }
      a00 += dot4f(pA[kq], x0); a01 += dot4f(pA[kq], x1);
      a10 += dot4f(pB[kq], x0); a11 += dot4f(pB[kq], x1);
      if (kq < 23) { x0 = nx0; x1 = nx1; }
    }
    if (it < 9) {
      float2 xo0 = *(const float2*)(x0p + r0);
      float2 xo1 = *(const float2*)(x1p + r0);
      float z00 = fminf(fmaxf(2.f*a00 - xo0.x, lo), 1000.f);
      float z10 = fminf(fmaxf(2.f*a10 - xo0.y, lo), 1000.f);
      float z01 = fminf(fmaxf(2.f*a01 - xo1.x, lo), 1000.f);
      float z11 = fminf(fmaxf(2.f*a11 - xo1.y, lo), 1000.f);
      *(float2*)(nxtb + e0*100 + r0) =
          make_float2(xo0.x + z00 - a00, xo0.y + z10 - a10);
      *(float2*)(nxtb + (e0+1)*100 + r0) =
          make_float2(xo1.x + z01 - a01, xo1.y + z11 - a11);
      __syncthreads();
      float* t = (float*)curb; curb = nxtb; nxtb = t;
    } else {
      if (r0 < 64) {
        *(float2*)&outg[(gbase + e0    )*64 + r0] = make_float2(a00, a10);
        *(float2*)&outg[(gbase + e0 + 1)*64 + r0] = make_float2(a01, a11);
      }
    }
  }
}

// ---------------------------------------------------------------- launch
extern "C" void kernel_launch(void* const* d_in, const int* in_sizes, int n_in,
                              void* d_out, int out_size, void* d_ws, size_t ws_size,
                              hipStream_t stream) {
  const float* x     = (const float*)d_in[0];   // (4096, 96)
  const float* parms = (const float*)d_in[1];   // (4096, 112)
  const float* Qg    = (const float*)d_in[2];   // (64, 64)
  const float* Ag    = (const float*)d_in[3];   // (16, 64)
  const float* Gg    = (const float*)d_in[4];   // (32, 64)
  float* out = (float*)d_out;                   // (4096, 64)

  float* ws  = (float*)d_ws;
  float* Pg  = ws;               // 96*96  = 9216
  float* Bg  = ws + 9216;        // 96*112 = 10752

  prep_kernel<<<1, 256, 0, stream>>>(Qg, Ag, Gg, Pg, Bg);
  iter_kernel<<<4096 / EB, 384, 0, stream>>>(x, parms, Pg, Bg, out);
}

// Round 13
// 78.614 us; speedup vs baseline: 1.5442x; 1.0022x over previous
//
#include <hip/hip_runtime.h>

// DR splitting solver. BATCH=4096, N=96 (64 x + 32 s), M=48 (16 eq + 32 ineq).
// JF and Hessian are batch-independent => prox_g1 is an affine map y = P x + Bmat p.
//   S=(I+Q)^{-1}; T=S Jx^T; K2=Jx T+diag(0,I32); R2=K2^{-1}[T^T|E];
//   P=diag(S,I)-[T;E^T]R2; Bmat=[-P[:,:64] | R2^T]
// Iterate 10x: y=Px+c; x += clamp(2y-x,l,u)-y; out=y[:64].
//
// Round-12 lesson: iter's "register-resident P" never happened -- Pg is
// __restrict__ const, so the compiler legally SANK the P loads into the 10-iter
// loop (VGPR 132, FETCH 2MB/dispatch = P re-streamed from L2 every iteration,
// ~22us of L2 traffic). Round-13: asm volatile memory clobber after the P loads
// forces the values live in registers (re-load would be unsound). prep = proven
// round-9 shape (42us, VGPR 104), untouched.

__device__ __forceinline__ float dot4f(float4 a, float4 b) {
  return a.x*b.x + a.y*b.y + a.z*b.z + a.w*b.w;
}
__device__ __forceinline__ void ld4(const float* p, float* d) {
  float4 v = *(const float4*)p;
  d[0] = v.x; d[1] = v.y; d[2] = v.z; d[3] = v.w;
}
__device__ __forceinline__ void st4(float* p, const float* s) {
  *(float4*)p = make_float4(s[0], s[1], s[2], s[3]);
}
__device__ __forceinline__ float fastrcp(float x) {
  float r = __builtin_amdgcn_rcpf(x);
  return r * (2.0f - x * r);     // 1 Newton step: ~1e-7 rel
}
// W = A*B (4x4)
__device__ __forceinline__ void mm4(float W[4][4], const float A[4][4], const float B[4][4]) {
  #pragma unroll
  for (int r = 0; r < 4; ++r)
    #pragma unroll
    for (int q = 0; q < 4; ++q) {
      float s = A[r][0]*B[0][q];
      #pragma unroll
      for (int k = 1; k < 4; ++k) s += A[r][k]*B[k][q];
      W[r][q] = s;
    }
}
// in-place 4x4 inverse by GJ, no pivoting (SPD principal blocks)
__device__ __forceinline__ void inv4(float D[4][4]) {
  #pragma unroll
  for (int p = 0; p < 4; ++p) {
    float pi = fastrcp(D[p][p]);
    D[p][p] = pi;
    #pragma unroll
    for (int q = 0; q < 4; ++q) if (q != p) D[p][q] *= pi;
    #pragma unroll
    for (int i = 0; i < 4; ++i) if (i != p) {
      float f = D[i][p];
      #pragma unroll
      for (int q = 0; q < 4; ++q) if (q != p) D[i][q] -= f * D[p][q];
      D[i][p] = -f * pi;
    }
  }
}

// one double-buffered block-GJ step, stride 68 (64x64), all 256 threads
__device__ __forceinline__ void gj_step64(const float* __restrict__ src,
                                          float* __restrict__ dst,
                                          int b, int ig, int jg) {
  float D[4][4], C[4][4], R[4][4], T4[4][4], W[4][4];
  #pragma unroll
  for (int r = 0; r < 4; ++r) {
    ld4(&src[(4*b + r)*68 + 4*b],  D[r]);
    ld4(&src[(4*ig + r)*68 + 4*b], C[r]);
    ld4(&src[(4*b + r)*68 + 4*jg], R[r]);
    ld4(&src[(4*ig + r)*68 + 4*jg], T4[r]);
  }
  inv4(D);
  if (ig == b) {
    if (jg == b) {
      #pragma unroll
      for (int r = 0; r < 4; ++r)
        #pragma unroll
        for (int q = 0; q < 4; ++q) W[r][q] = D[r][q];
    } else {
      mm4(W, D, R);
    }
  } else {
    float E[4][4];
    mm4(E, C, D);
    if (jg == b) {
      #pragma unroll
      for (int r = 0; r < 4; ++r)
        #pragma unroll
        for (int q = 0; q < 4; ++q) W[r][q] = -E[r][q];
    } else {
      #pragma unroll
      for (int r = 0; r < 4; ++r)
        #pragma unroll
        for (int q = 0; q < 4; ++q) {
          float s = T4[r][q];
          #pragma unroll
          for (int k = 0; k < 4; ++k) s -= E[r][k] * R[k][q];
          W[r][q] = s;
        }
    }
  }
  #pragma unroll
  for (int r = 0; r < 4; ++r) st4(&dst[(4*ig + r)*68 + 4*jg], W[r]);
  __syncthreads();
}

// one double-buffered block-GJ step, stride 52 (48x48), threads 0..143 active
__device__ __forceinline__ void gj_step48(const float* __restrict__ src,
                                          float* __restrict__ dst,
                                          int b, int tid) {
  const bool act = tid < 144;
  const int ig = tid / 12, jg = tid - (tid / 12) * 12;
  float D[4][4], C[4][4], R[4][4], T4[4][4], W[4][4];
  if (act) {
    #pragma unroll
    for (int r = 0; r < 4; ++r) {
      ld4(&src[(4*b + r)*52 + 4*b],  D[r]);
      ld4(&src[(4*ig + r)*52 + 4*b], C[r]);
      ld4(&src[(4*b + r)*52 + 4*jg], R[r]);
      ld4(&src[(4*ig + r)*52 + 4*jg], T4[r]);
    }
    inv4(D);
    if (ig == b) {
      if (jg == b) {
        #pragma unroll
        for (int r = 0; r < 4; ++r)
          #pragma unroll
          for (int q = 0; q < 4; ++q) W[r][q] = D[r][q];
      } else {
        mm4(W, D, R);
      }
    } else {
      float E[4][4];
      mm4(E, C, D);
      if (jg == b) {
        #pragma unroll
        for (int r = 0; r < 4; ++r)
          #pragma unroll
          for (int q = 0; q < 4; ++q) W[r][q] = -E[r][q];
      } else {
        #pragma unroll
        for (int r = 0; r < 4; ++r)
          #pragma unroll
          for (int q = 0; q < 4; ++q) {
            float s = T4[r][q];
            #pragma unroll
            for (int k = 0; k < 4; ++k) s -= E[r][k] * R[k][q];
            W[r][q] = s;
          }
      }
    }
    #pragma unroll
    for (int r = 0; r < 4; ++r) st4(&dst[(4*ig + r)*52 + 4*jg], W[r]);
  }
  __syncthreads();
}

// ---------------------------------------------------------------- kernel A
__global__ __launch_bounds__(256, 1) void prep_kernel(
    const float* __restrict__ Qg, const float* __restrict__ Ag,
    const float* __restrict__ Gg,
    float* __restrict__ Pg, float* __restrict__ Bg)
{
  // floats: 4352 + 4352 + 2496 + 4608 = 15808 = 63232 B
  __shared__ float sMa[64*68];   // M1 ping  -> S (after 16 steps)
  __shared__ float sMb[64*68];   // M1 pong  -> T (64x48, stride 48)
  __shared__ float sK [48*52];   // K2 ping  -> Ki
  __shared__ float sR2[48*96];   // Jx (s68) -> K2 pong (s52) -> R2 (s96)

#define SM_(i,j) sMa[(i)*68+(j)]
#define TT_(i,j) sMb[(i)*48+(j)]
#define SK_(i,j) sK[(i)*52+(j)]
#define JX_(a,k) sR2[(a)*68+(k)]

  const int tid = threadIdx.x;
  const int ig = tid >> 4, jg = tid & 15;

  // ---- stage Jx = [A;G] (48x64, stride 68) and M1 = Q + I
  {
    const float4* A4 = (const float4*)Ag;          // 256 quads
    const float4* G4 = (const float4*)Gg;          // 512 quads
    {
      int t = tid;
      int a = t >> 4, kc = t & 15;
      st4(&JX_(a, kc*4), (const float*)&A4[t]);
    }
    for (int t = tid; t < 512; t += 256) {
      int a = t >> 4, kc = t & 15;
      st4(&JX_(16 + a, kc*4), (const float*)&G4[t]);
    }
    const float4* Q4 = (const float4*)Qg;          // 1024 quads
    for (int t = tid; t < 1024; t += 256) {
      int i = t >> 4, kc = t & 15;
      st4(&SM_(i, kc*4), (const float*)&Q4[t]);
    }
  }
  __syncthreads();
  if (tid < 64) SM_(tid, tid) += 1.0f;
  __syncthreads();

  // ---- block-GJ 64 (dbuf, 1 barrier/step, 16 steps) -> S in sMa
  #pragma unroll 1
  for (int p = 0; p < 8; ++p) {
    gj_step64(sMa, sMb, 2*p,     ig, jg);
    gj_step64(sMb, sMa, 2*p + 1, ig, jg);
  }

  // ---- T = S Jx^T : 4x3 register tile/thread (16 ig x 16 jg covers 64x48)
  {
    const int i0 = 4*ig, j0 = 3*jg;
    float acc[4][3] = {};
    #pragma unroll 4
    for (int kq = 0; kq < 16; ++kq) {
      float sv[4][4], jv[3][4];
      ld4(&SM_(i0+0, kq*4), sv[0]); ld4(&SM_(i0+1, kq*4), sv[1]);
      ld4(&SM_(i0+2, kq*4), sv[2]); ld4(&SM_(i0+3, kq*4), sv[3]);
      ld4(&JX_(j0+0, kq*4), jv[0]); ld4(&JX_(j0+1, kq*4), jv[1]);
      ld4(&JX_(j0+2, kq*4), jv[2]);
      #pragma unroll
      for (int r = 0; r < 4; ++r)
        #pragma unroll
        for (int c = 0; c < 3; ++c)
          #pragma unroll
          for (int s = 0; s < 4; ++s)
            acc[r][c] += sv[r][s] * jv[c][s];
    }
    __syncthreads();   // SM/JX reads done before TT writes to sMb pong
    #pragma unroll
    for (int r = 0; r < 4; ++r)
      #pragma unroll
      for (int c = 0; c < 3; ++c)
        TT_(i0+r, j0+c) = acc[r][c];
  }
  __syncthreads();

  // ---- K2 = Jx T + diag(0,I32)  (192 threads, 3x4 tiles)
  if (tid < 192) {
    int ag = tid / 12, bg = tid - ag*12;
    int a0 = ag*3, b0 = bg*4;
    float acc[3][4] = {};
    #pragma unroll 4
    for (int k = 0; k < 64; ++k) {
      float4 tb = *(const float4*)&TT_(k,b0);
      #pragma unroll
      for (int r = 0; r < 3; ++r) {
        float jv = JX_(a0 + r, k);
        acc[r][0] += jv*tb.x; acc[r][1] += jv*tb.y;
        acc[r][2] += jv*tb.z; acc[r][3] += jv*tb.w;
      }
    }
    #pragma unroll
    for (int r = 0; r < 3; ++r)
      #pragma unroll
      for (int q = 0; q < 4; ++q) {
        int a = a0 + r, b = b0 + q;
        SK_(a,b) = acc[r][q] + ((a == b && a >= 16) ? 1.0f : 0.0f);
      }
  }
  __syncthreads();

  // ---- block-GJ 48 (dbuf; pong overlays dead Jx region) -> Ki in sK
  {
    float* KP = sR2;   // 48*52 = 2496 <= 4608
    #pragma unroll 1
    for (int p = 0; p < 6; ++p) {
      gj_step48(sK, KP, 2*p,     tid);
      gj_step48(KP, sK, 2*p + 1, tid);
    }
  }
  // KP / JX dead; sR2 region becomes R2 (stride 96).

  // ---- R2 cols<64: R2[k][c] = sum_m Ki[k][m]*T[c][m]  (3k x 4c tiles)
  {
    int kg = tid >> 4, cg = tid & 15;
    int k0 = kg*3, c0 = cg*4;
    float acc[3][4] = {};
    #pragma unroll 4
    for (int m = 0; m < 48; m += 4) {
      float kv[3][4], tv[4][4];
      ld4(&SK_(k0+0,m), kv[0]); ld4(&SK_(k0+1,m), kv[1]); ld4(&SK_(k0+2,m), kv[2]);
      ld4(&TT_(c0+0,m), tv[0]); ld4(&TT_(c0+1,m), tv[1]);
      ld4(&TT_(c0+2,m), tv[2]); ld4(&TT_(c0+3,m), tv[3]);
      #pragma unroll
      for (int r = 0; r < 3; ++r)
        #pragma unroll
        for (int q = 0; q < 4; ++q)
          #pragma unroll
          for (int s = 0; s < 4; ++s)
            acc[r][q] += kv[r][s] * tv[q][s];
    }
    #pragma unroll
    for (int r = 0; r < 3; ++r)
      #pragma unroll
      for (int q = 0; q < 4; ++q) {
        int k = k0 + r, c = c0 + q;
        float v = acc[r][q];
        sR2[k*96 + c] = v;
        Bg[c*112 + 64 + k] = v;       // Bmat[:,64:] = R2^T
      }
  }
  // R2 cols>=64 (selection from Ki)
  #pragma unroll 1
  for (int t = tid; t < 48*32; t += 256) {
    int k = t >> 5, j = t & 31;
    float v = SK_(k, 16 + j);
    sR2[k*96 + 64 + j] = v;
    Bg[(64 + j)*112 + 64 + k] = v;
  }
  __syncthreads();

  // ---- P heavy rows (i<64): P = S_diag - T*R2  (16 ig x 24 jc tasks)
  #pragma unroll 1
  for (int task = tid; task < 384; task += 256) {
    int tg = task / 24, jc = task - tg*24;
    int i0 = tg*4, j0 = jc*4;
    float acc[4][4];
    #pragma unroll
    for (int r = 0; r < 4; ++r)
      #pragma unroll
      for (int q = 0; q < 4; ++q)
        acc[r][q] = (j0 < 64) ? SM_(i0+r, j0+q) : 0.0f;
    #pragma unroll 4
    for (int m = 0; m < 48; m += 4) {
      float tv[4][4], rv[4][4];
      ld4(&TT_(i0+0,m), tv[0]); ld4(&TT_(i0+1,m), tv[1]);
      ld4(&TT_(i0+2,m), tv[2]); ld4(&TT_(i0+3,m), tv[3]);
      ld4(&sR2[(m+0)*96 + j0], rv[0]);
      ld4(&sR2[(m+1)*96 + j0], rv[1]);
      ld4(&sR2[(m+2)*96 + j0], rv[2]);
      ld4(&sR2[(m+3)*96 + j0], rv[3]);
      #pragma unroll
      for (int r = 0; r < 4; ++r)
        #pragma unroll
        for (int q = 0; q < 4; ++q)
          #pragma unroll
          for (int s = 0; s < 4; ++s)
            acc[r][q] -= tv[r][s] * rv[s][q];
    }
    #pragma unroll
    for (int r = 0; r < 4; ++r)
      #pragma unroll
      for (int q = 0; q < 4; ++q) {
        int i = i0 + r, j = j0 + q;
        float v = acc[r][q];
        Pg[i*96 + j] = v;
        if (j0 < 64) Bg[i*112 + j] = -v;   // Bmat[:,:64] = -P[:,:64]
      }
  }
  // ---- P rows >= 64: P[64+a][j] = (64+a==j) - R2[16+a][j]
  #pragma unroll 1
  for (int t = tid; t < 32*96; t += 256) {
    int a = t / 96, j = t - (t / 96) * 96;
    float v = ((64 + a) == j ? 1.0f : 0.0f) - sR2[(16 + a)*96 + j];
    Pg[(64 + a)*96 + j] = v;
    if (j < 64) Bg[(64 + a)*112 + j] = -v;
  }
#undef SM_
#undef TT_
#undef SK_
#undef JX_
}

// ---------------------------------------------------------------- kernel B
#define EB 16   // elements per block; grid = 256 blocks x 384 threads

__global__ __launch_bounds__(384)
__attribute__((amdgpu_waves_per_eu(1, 2)))
void iter_kernel(
    const float* __restrict__ xg, const float* __restrict__ pg,
    const float* Pg, const float* __restrict__ Bg,
    float* __restrict__ outg)
{
  // Thread (eg 0..7, rg 0..47): P rows {2rg, 2rg+1} in registers. The asm
  // memory clobber after the loads makes re-loading P inside the loop unsound,
  // so the compiler MUST keep the 192 values live (waves_per_eu(1,2) lifts the
  // VGPR ceiling to permit it). x double-buffered in LDS, 1-ahead prefetch.
  __shared__ float sX[2][EB][100];
  __shared__ float sPar[EB][112];

  const int tid = threadIdx.x;          // 0..383
  const int gbase = blockIdx.x * EB;
  const int eg = tid / 48;              // 0..7
  const int rg = tid - 48 * eg;         // 0..47
  const int e0 = 2 * eg, r0 = 2 * rg;

  // stage x (384 quads, exactly 1/thread) and parms (448 quads)
  const float4* X4 = (const float4*)xg;
  {
    int e = tid / 24, kc = tid - 24 * (tid / 24);
    *(float4*)&sX[0][e][kc*4] = X4[gbase*24 + tid];
  }
  const float4* Par4 = (const float4*)pg;
  for (int t = tid; t < EB*28; t += 384) {
    int e = t / 28, jc = t - 28 * e;
    *(float4*)&sPar[e][jc*4] = Par4[gbase*28 + t];
  }

  // my 2 P rows -> registers, then pin them live (no re-load possible after
  // the memory clobber: the compiler must keep all 48 float4 in VGPRs)
  float4 pA[24], pB[24];
  const float4* P4 = (const float4*)Pg;
  #pragma unroll
  for (int kq = 0; kq < 24; ++kq) pA[kq] = P4[r0*24 + kq];
  #pragma unroll
  for (int kq = 0; kq < 24; ++kq) pB[kq] = P4[(r0+1)*24 + kq];
  asm volatile("" ::: "memory");

  __syncthreads();

  // c = Bmat(rows r0,r0+1) @ parms(elems e0,e0+1)
  float c00 = 0.f, c01 = 0.f, c10 = 0.f, c11 = 0.f;
  {
    const float4* B4 = (const float4*)Bg;
    #pragma unroll 4
    for (int jc = 0; jc < 28; ++jc) {
      float4 b0 = B4[r0*28 + jc];
      float4 b1 = B4[(r0+1)*28 + jc];
      float4 q0 = *(const float4*)&sPar[e0    ][jc*4];
      float4 q1 = *(const float4*)&sPar[e0 + 1][jc*4];
      c00 += dot4f(b0, q0); c01 += dot4f(b0, q1);
      c10 += dot4f(b1, q0); c11 += dot4f(b1, q1);
    }
  }

  const float lo = (r0 < 64) ? -1000.0f : 0.0f;
  const float* curb = &sX[0][0][0];
  float* nxtb = &sX[1][0][0];

  #pragma unroll 1
  for (int it = 0; it < 10; ++it) {
    float a00 = c00, a01 = c01, a10 = c10, a11 = c11;
    const float* x0p = curb + e0 * 100;
    const float* x1p = x0p + 100;
    float4 x0 = *(const float4*)(x0p);
    float4 x1 = *(const float4*)(x1p);
    #pragma unroll
    for (int kq = 0; kq < 24; ++kq) {
      float4 nx0, nx1;
      if (kq < 23) {                       // prefetch next quad pair
        nx0 = *(const float4*)(x0p + (kq+1)*4);
        nx1 = *(const float4*)(x1p + (kq+1)*4);
      }
      a00 += dot4f(pA[kq], x0); a01 += dot4f(pA[kq], x1);
      a10 += dot4f(pB[kq], x0); a11 += dot4f(pB[kq], x1);
      if (kq < 23) { x0 = nx0; x1 = nx1; }
    }
    if (it < 9) {
      float2 xo0 = *(const float2*)(x0p + r0);
      float2 xo1 = *(const float2*)(x1p + r0);
      float z00 = fminf(fmaxf(2.f*a00 - xo0.x, lo), 1000.f);
      float z10 = fminf(fmaxf(2.f*a10 - xo0.y, lo), 1000.f);
      float z01 = fminf(fmaxf(2.f*a01 - xo1.x, lo), 1000.f);
      float z11 = fminf(fmaxf(2.f*a11 - xo1.y, lo), 1000.f);
      *(float2*)(nxtb + e0*100 + r0) =
          make_float2(xo0.x + z00 - a00, xo0.y + z10 - a10);
      *(float2*)(nxtb + (e0+1)*100 + r0) =
          make_float2(xo1.x + z01 - a01, xo1.y + z11 - a11);
      __syncthreads();
      float* t = (float*)curb; curb = nxtb; nxtb = t;
    } else {
      if (r0 < 64) {
        *(float2*)&outg[(gbase + e0    )*64 + r0] = make_float2(a00, a10);
        *(float2*)&outg[(gbase + e0 + 1)*64 + r0] = make_float2(a01, a11);
      }
    }
  }
}

// ---------------------------------------------------------------- launch
extern "C" void kernel_launch(void* const* d_in, const int* in_sizes, int n_in,
                              void* d_out, int out_size, void* d_ws, size_t ws_size,
                              hipStream_t stream) {
  const float* x     = (const float*)d_in[0];   // (4096, 96)
  const float* parms = (const float*)d_in[1];   // (4096, 112)
  const float* Qg    = (const float*)d_in[2];   // (64, 64)
  const float* Ag    = (const float*)d_in[3];   // (16, 64)
  const float* Gg    = (const float*)d_in[4];   // (32, 64)
  float* out = (float*)d_out;                   // (4096, 64)

  float* ws  = (float*)d_ws;
  float* Pg  = ws;               // 96*96  = 9216
  float* Bg  = ws + 9216;        // 96*112 = 10752

  prep_kernel<<<1, 256, 0, stream>>>(Qg, Ag, Gg, Pg, Bg);
  iter_kernel<<<4096 / EB, 384, 0, stream>>>(x, parms, Pg, Bg, out);
}